// Round 4
// baseline (162.227 us; speedup 1.0000x reference)
//
#include <hip/hip_runtime.h>

// smartorn layer: out[b,j] = elu(power[j] * sum_i x[b,i]*gate(i,j) - bias[j])
// gate(i,j) = strength(dpb . outdir_i) * strength(dpb . indir_j)
//   dp = pos_j - pos_i, dpb = dp / sqrt(max(|dp|^2, 1e-5))
//   strength(v) = (exp(v) - e^-1) / (e - e^-1)
//
// All tensors float32. Inner-loop i is wave-uniform -> per-i operands are
// scalar (packed 64 B/record, uniform s_load). j per-lane, B=8 accumulators
// in VGPRs (v_pk_fma_f32 pairs). Deterministic i-split (16 slabs); the LAST
// finishing block of each j-tile (device-scope atomic counter + threadfence
// release/acquire) reduces the 16 slabs, applies power/bias/elu, writes out.
// dur_us is dominated by the harness's 2x ~40us 256MiB ws-poison fills; this
// round removes the last reachable ~2-3us (phase2 launch + 2MB re-read).

#define NN 4096
#define NB 8
#define JT 64               // j per block (one wave of 64 j-lanes)
#define ISPLIT 16           // i-splits per j-tile
#define IPB (NN / ISPLIT)   // 256 i per block
#define IPW (IPB / 4)       // 64 i per wave
#define PACK_FLOATS (NN * 16)

typedef __attribute__((ext_vector_type(2))) float f2;

__global__ __launch_bounds__(256) void smartorn_pack(
    const float* __restrict__ x,       // (B, N)
    const float* __restrict__ pos,     // (N, 3)
    const float* __restrict__ outdir,  // (N, 3)
    float* __restrict__ pack)          // (N, 16)
{
    const int i = blockIdx.x * 256 + threadIdx.x;
    if (i >= NN) return;
    float4* p = (float4*)(pack + (size_t)i * 16);
    p[0] = make_float4(pos[i * 3 + 0], pos[i * 3 + 1], pos[i * 3 + 2],
                       outdir[i * 3 + 0]);
    p[1] = make_float4(outdir[i * 3 + 1], outdir[i * 3 + 2],
                       x[0 * NN + i], x[1 * NN + i]);
    p[2] = make_float4(x[2 * NN + i], x[3 * NN + i],
                       x[4 * NN + i], x[5 * NN + i]);
    p[3] = make_float4(x[6 * NN + i], x[7 * NN + i], 0.f, 0.f);
}

__global__ __launch_bounds__(256) void smartorn_main(
    const float* __restrict__ pack,    // (N, 16)
    const float* __restrict__ pos,     // (N, 3)
    const float* __restrict__ indir,   // (N, 3)
    const float* __restrict__ power,   // (N)
    const float* __restrict__ bias,    // (N)
    float* __restrict__ part,          // (ISPLIT, B, N)
    int* __restrict__ cnt,             // (N/JT) zeroed counters
    float* __restrict__ out)           // (B, N)
{
    __shared__ float sacc[4][JT][NB];
    __shared__ int sdone;

    const int jt  = blockIdx.x / ISPLIT;
    const int is  = blockIdx.x % ISPLIT;
    const int tid = threadIdx.x;
    const int tj  = tid & 63;
    const int sub = __builtin_amdgcn_readfirstlane(tid >> 6);  // wave-uniform

    const int j = jt * JT + tj;
    const float pjx = pos[j * 3 + 0];
    const float pjy = pos[j * 3 + 1];
    const float pjz = pos[j * 3 + 2];
    const float inx = indir[j * 3 + 0];
    const float iny = indir[j * 3 + 1];
    const float inz = indir[j * 3 + 2];

    f2 a01 = {0.f, 0.f}, a23 = {0.f, 0.f}, a45 = {0.f, 0.f}, a67 = {0.f, 0.f};

    const float C1 = 0.36787944117144233f;  // e^-1
    const float SC = 0.18101541533756566f;  // 1 / (e - e^-1)^2

    // uniform base -> pk[] accesses compile to scalar s_load
    const float4* pk = (const float4*)pack + (size_t)(is * IPB + sub * IPW) * 4;

#pragma unroll 2
    for (int il = 0; il < IPW; ++il) {
        const float4 q0 = pk[il * 4 + 0];   // {px, py, pz, ox}
        const float4 q1 = pk[il * 4 + 1];   // {oy, oz, x0, x1}
        const float4 q2 = pk[il * 4 + 2];   // {x2, x3, x4, x5}
        const float4 q3 = pk[il * 4 + 3];   // {x6, x7, -, -}

        const float dx = pjx - q0.x;
        const float dy = pjy - q0.y;
        const float dz = pjz - q0.z;
        float n2 = fmaf(dx, dx, fmaf(dy, dy, dz * dz));
        n2 = fmaxf(n2, 1e-5f);
        const float inv = rsqrtf(n2);
        const float da = fmaf(dx, q0.w, fmaf(dy, q1.x, dz * q1.y)) * inv;
        const float db = fmaf(dx, inx, fmaf(dy, iny, dz * inz)) * inv;
        const float g = (__expf(da) - C1) * (__expf(db) - C1) * SC;

        const f2 gv = {g, g};
        a01 = __builtin_elementwise_fma((f2){q1.z, q1.w}, gv, a01);
        a23 = __builtin_elementwise_fma((f2){q2.x, q2.y}, gv, a23);
        a45 = __builtin_elementwise_fma((f2){q2.z, q2.w}, gv, a45);
        a67 = __builtin_elementwise_fma((f2){q3.x, q3.y}, gv, a67);
    }

    sacc[sub][tj][0] = a01.x;  sacc[sub][tj][1] = a01.y;
    sacc[sub][tj][2] = a23.x;  sacc[sub][tj][3] = a23.y;
    sacc[sub][tj][4] = a45.x;  sacc[sub][tj][5] = a45.y;
    sacc[sub][tj][6] = a67.x;  sacc[sub][tj][7] = a67.y;
    __syncthreads();

    for (int p = tid; p < JT * NB; p += 256) {
        const int bb = p >> 6;
        const int jj = p & 63;
        const float s = sacc[0][jj][bb] + sacc[1][jj][bb] +
                        sacc[2][jj][bb] + sacc[3][jj][bb];
        part[(is * NB + bb) * NN + jt * JT + jj] = s;
    }

    // ---- last block of this j-tile reduces the 16 slabs ----
    __threadfence();                       // release partials (device scope)
    if (tid == 0) sdone = atomicAdd(&cnt[jt], 1);
    __syncthreads();
    if (sdone != ISPLIT - 1) return;
    __threadfence();                       // acquire other blocks' partials

    for (int p = tid; p < JT * NB; p += 256) {
        const int bb = p >> 6;
        const int jj = p & 63;
        const int jg = jt * JT + jj;
        float s = 0.f;
#pragma unroll
        for (int is2 = 0; is2 < ISPLIT; ++is2)
            s += part[(is2 * NB + bb) * NN + jg];
        const float v = fmaf(s, power[jg], -bias[jg]);
        out[bb * NN + jg] = v > 0.f ? v : expm1f(v);
    }
}

extern "C" void kernel_launch(void* const* d_in, const int* in_sizes, int n_in,
                              void* d_out, int out_size, void* d_ws, size_t ws_size,
                              hipStream_t stream) {
    const float* x      = (const float*)d_in[0];
    const float* pos    = (const float*)d_in[1];
    const float* indir  = (const float*)d_in[2];
    const float* outdir = (const float*)d_in[3];
    const float* power  = (const float*)d_in[4];
    const float* bias   = (const float*)d_in[5];
    float* ws   = (float*)d_ws;
    float* pack = ws;                               // 256 KiB
    float* part = ws + PACK_FLOATS;                 // 2 MiB
    int*   cnt  = (int*)(part + ISPLIT * NB * NN);  // 64 ints (poisoned -> zero)
    float* out  = (float*)d_out;

    hipMemsetAsync(cnt, 0, (NN / JT) * sizeof(int), stream);

    dim3 block(256);
    hipLaunchKernelGGL(smartorn_pack, dim3(NN / 256), block, 0, stream,
                       x, pos, outdir, pack);
    hipLaunchKernelGGL(smartorn_main, dim3((NN / JT) * ISPLIT), block, 0, stream,
                       pack, pos, indir, power, bias, part, cnt, out);
}

// Round 5
// 83.071 us; speedup vs baseline: 1.9529x; 1.9529x over previous
//
#include <hip/hip_runtime.h>

// smartorn layer: out[b,j] = elu(power[j] * sum_i x[b,i]*gate(i,j) - bias[j])
// gate(i,j) = strength(dpb . outdir_i) * strength(dpb . indir_j)
//   dp = pos_j - pos_i, dpb = dp / sqrt(max(|dp|^2, 1e-5))
//   strength(v) = (exp(v) - e^-1) / (e - e^-1)
//
// All tensors float32. R4 post-mortem: device fences (threadfence+atomic
// last-block reduce) cost 70us on 8-XCD CDNA4 -- reverted. R2/R3 ~40us came
// from per-i operand delivery (LDS-issue / smem-latency bound at 1 j/lane).
// R5: 4 j per lane -> one 64B i-record (4x broadcast ds_read_b128, conflict-
// free) feeds 256 pairs; VALU-bound at ~0.75 cyc/pair. 4 waves/block share a
// staged 64-record chunk, reduce via LDS (deterministic), 64 i-slabs in ws,
// tiny phase2 does slab-sum + power/bias/elu. No fences, no atomics.

#define NN 4096
#define NB 8
#define RJ 4                 // j per lane
#define JTILE 256            // j per block (= 64 lanes * RJ)
#define IPB 64               // i per block chunk
#define IPW 16               // i per wave (4 waves split the chunk)
#define NSLAB (NN / IPB)     // 64 deterministic i-slabs

typedef __attribute__((ext_vector_type(2))) float f2;

__global__ __launch_bounds__(256, 4) void smartorn_phase1(
    const float* __restrict__ x,       // (B, N)
    const float* __restrict__ pos,     // (N, 3)
    const float* __restrict__ indir,   // (N, 3)
    const float* __restrict__ outdir,  // (N, 3)
    float* __restrict__ part)          // (NSLAB, B, N)
{
    __shared__ float4 srec[IPB * 4];           // 4 KB: 64 B per i-record
    __shared__ float  sacc[4][NB][JTILE];      // 32 KB: per-wave partials

    const int bI   = blockIdx.x;
    const int jt   = bI >> 6;    // 0..15  j-tile
    const int is   = bI & 63;    // 0..63  i-slab
    const int tid  = threadIdx.x;
    const int lane = tid & 63;
    const int w    = __builtin_amdgcn_readfirstlane(tid >> 6);

    // ---- stage the block's 64 i-records (thread t -> record t/4, quad t%4) ----
    {
        const int r  = tid >> 2;
        const int q  = tid & 3;
        const int gi = is * IPB + r;
        float4 v;
        if (q == 0)
            v = make_float4(pos[gi * 3 + 0], pos[gi * 3 + 1], pos[gi * 3 + 2],
                            outdir[gi * 3 + 0]);
        else if (q == 1)
            v = make_float4(outdir[gi * 3 + 1], outdir[gi * 3 + 2],
                            x[0 * NN + gi], x[1 * NN + gi]);
        else if (q == 2)
            v = make_float4(x[2 * NN + gi], x[3 * NN + gi],
                            x[4 * NN + gi], x[5 * NN + gi]);
        else
            v = make_float4(x[6 * NN + gi], x[7 * NN + gi], 0.f, 0.f);
        srec[r * 4 + q] = v;
    }

    // ---- per-lane j-state: RJ receivers ----
    float pjx[RJ], pjy[RJ], pjz[RJ], inx[RJ], iny[RJ], inz[RJ];
#pragma unroll
    for (int r = 0; r < RJ; ++r) {
        const int jg = jt * JTILE + r * 64 + lane;
        pjx[r] = pos[jg * 3 + 0];
        pjy[r] = pos[jg * 3 + 1];
        pjz[r] = pos[jg * 3 + 2];
        inx[r] = indir[jg * 3 + 0];
        iny[r] = indir[jg * 3 + 1];
        inz[r] = indir[jg * 3 + 2];
    }

    __syncthreads();

    f2 acc[RJ][4];
#pragma unroll
    for (int r = 0; r < RJ; ++r)
#pragma unroll
        for (int k = 0; k < 4; ++k) acc[r][k] = (f2){0.f, 0.f};

    const float C1 = 0.36787944117144233f;  // e^-1
    const float SC = 0.18101541533756566f;  // 1 / (e - e^-1)^2

    const float4* S = &srec[w * IPW * 4];   // wave-uniform base -> broadcast reads

#pragma unroll 2
    for (int s = 0; s < IPW; ++s) {
        const float4 q0 = S[s * 4 + 0];   // {px, py, pz, ox}
        const float4 q1 = S[s * 4 + 1];   // {oy, oz, x0, x1}
        const float4 q2 = S[s * 4 + 2];   // {x2, x3, x4, x5}
        const float4 q3 = S[s * 4 + 3];   // {x6, x7, -, -}

#pragma unroll
        for (int r = 0; r < RJ; ++r) {
            const float dx = pjx[r] - q0.x;
            const float dy = pjy[r] - q0.y;
            const float dz = pjz[r] - q0.z;
            float n2 = fmaf(dx, dx, fmaf(dy, dy, dz * dz));
            n2 = fmaxf(n2, 1e-5f);
            const float inv = rsqrtf(n2);
            const float da = fmaf(dx, q0.w, fmaf(dy, q1.x, dz * q1.y)) * inv;
            const float db = fmaf(dx, inx[r], fmaf(dy, iny[r], dz * inz[r])) * inv;
            const float g = (__expf(da) - C1) * (__expf(db) - C1) * SC;
            const f2 gv = {g, g};
            acc[r][0] = __builtin_elementwise_fma((f2){q1.z, q1.w}, gv, acc[r][0]);
            acc[r][1] = __builtin_elementwise_fma((f2){q2.x, q2.y}, gv, acc[r][1]);
            acc[r][2] = __builtin_elementwise_fma((f2){q2.z, q2.w}, gv, acc[r][2]);
            acc[r][3] = __builtin_elementwise_fma((f2){q3.x, q3.y}, gv, acc[r][3]);
        }
    }

    // ---- dump per-wave partials (stride-1 across lanes: conflict-free) ----
#pragma unroll
    for (int r = 0; r < RJ; ++r) {
        const int jp = r * 64 + lane;
#pragma unroll
        for (int k = 0; k < 4; ++k) {
            sacc[w][2 * k + 0][jp] = acc[r][k].x;
            sacc[w][2 * k + 1][jp] = acc[r][k].y;
        }
    }
    __syncthreads();

    // ---- cross-wave reduce, write slab (coalesced 256-wide) ----
#pragma unroll
    for (int b = 0; b < NB; ++b) {
        const float s = sacc[0][b][tid] + sacc[1][b][tid] +
                        sacc[2][b][tid] + sacc[3][b][tid];
        part[(is * NB + b) * NN + jt * JTILE + tid] = s;
    }
}

__global__ __launch_bounds__(256) void smartorn_phase2(
    const float* __restrict__ part,    // (NSLAB, B, N)
    const float* __restrict__ power,   // (N)
    const float* __restrict__ bias,    // (N)
    float* __restrict__ out)           // (B, N)
{
    const int t = blockIdx.x * 256 + threadIdx.x;   // 0 .. B*N-1
    const int j = t & (NN - 1);
    const int b = t >> 12;
    float s = 0.f;
#pragma unroll 16
    for (int is = 0; is < NSLAB; ++is)
        s += part[(is * NB + b) * NN + j];
    const float v = fmaf(s, power[j], -bias[j]);
    out[t] = v > 0.f ? v : expm1f(v);
}

extern "C" void kernel_launch(void* const* d_in, const int* in_sizes, int n_in,
                              void* d_out, int out_size, void* d_ws, size_t ws_size,
                              hipStream_t stream) {
    const float* x      = (const float*)d_in[0];
    const float* pos    = (const float*)d_in[1];
    const float* indir  = (const float*)d_in[2];
    const float* outdir = (const float*)d_in[3];
    const float* power  = (const float*)d_in[4];
    const float* bias   = (const float*)d_in[5];
    float* part = (float*)d_ws;          // NSLAB*B*N*4 = 8 MiB
    float* out  = (float*)d_out;

    dim3 block(256);
    hipLaunchKernelGGL(smartorn_phase1, dim3((NN / JTILE) * NSLAB), block, 0, stream,
                       x, pos, indir, outdir, part);
    hipLaunchKernelGGL(smartorn_phase2, dim3((NB * NN) / 256), block, 0, stream,
                       part, power, bias, out);
}